// Round 12
// baseline (460.442 us; speedup 1.0000x reference)
//
#include <hip/hip_runtime.h>
#include <hip/hip_bf16.h>

#define N_NODES 50000
#define N_EDGES 640000
#define D 128
#define NPAD 50048   // 782 * 64
#define LAYERS 3
#define SCAN_NB 196  // ceil(50000/256)

typedef __attribute__((ext_vector_type(4))) float f32x4;
typedef __attribute__((ext_vector_type(8))) short bf16x8;
typedef __attribute__((ext_vector_type(4))) short bf16x4;

static __device__ __forceinline__ short f2bf(float f) {
    union { float f; unsigned u; } x; x.f = f;
    unsigned r = x.u + 0x7fffu + ((x.u >> 16) & 1u);  // RNE
    return (short)(r >> 16);
}
static __device__ __forceinline__ float ubits(unsigned u) {
    union { unsigned u; float f; } x; x.u = u; return x.f;
}

// direct global->LDS copy, 4B per lane: LDS[dst + lane*4] = *(gsrc_perlane)
static __device__ __forceinline__ void gload4(const void* g, void* l) {
    __builtin_amdgcn_global_load_lds((const __attribute__((address_space(1))) unsigned*)g,
                                     (__attribute__((address_space(3))) unsigned*)l, 4, 0, 0);
}

// ---------------- hb = bf16(x), row-major [node][128] ----------------
__global__ void init_kernel(const f32x4* __restrict__ in, bf16x4* __restrict__ hb) {
    int t = blockIdx.x * 256 + threadIdx.x;
    f32x4 v = in[t];
    bf16x4 p; p[0] = f2bf(v.x); p[1] = f2bf(v.y); p[2] = f2bf(v.z); p[3] = f2bf(v.w);
    hb[t] = p;
}

// ---------------- weights: wt[m][c][k] = bf16(W[m][k][c]) ----------------
__global__ void prepw_kernel(const float* __restrict__ W1, const float* __restrict__ W2,
                             short* __restrict__ wt) {
    int t = blockIdx.x * 256 + threadIdx.x;
    if (t >= 6 * 16384) return;
    int m = t >> 14, rem = t & 16383;
    int c = rem >> 7, k = rem & 127;
    const float* src = (m < 3) ? (W1 + m * 16384) : (W2 + (m - 3) * 16384);
    wt[m * 16384 + c * 128 + k] = f2bf(src[k * 128 + c]);
}

// ---------------- CSR build ----------------
__global__ void hist_kernel(const int* __restrict__ dst, int* __restrict__ deg) {
    int e = blockIdx.x * 256 + threadIdx.x;
    if (e < N_EDGES) atomicAdd(&deg[dst[e]], 1);
}

__global__ void scan1_kernel(const int* __restrict__ deg, int* __restrict__ rs,
                             int* __restrict__ bsum) {
    __shared__ int tmp[256];
    int i = blockIdx.x * 256 + threadIdx.x;
    int v = (i < N_NODES) ? deg[i] : 0;
    tmp[threadIdx.x] = v;
    __syncthreads();
    for (int off = 1; off < 256; off <<= 1) {
        int t = (threadIdx.x >= off) ? tmp[threadIdx.x - off] : 0;
        __syncthreads();
        tmp[threadIdx.x] += t;
        __syncthreads();
    }
    if (i < N_NODES) rs[i] = tmp[threadIdx.x] - v;  // exclusive
    if (threadIdx.x == 255) bsum[blockIdx.x] = tmp[255];
}

__global__ void scan2_kernel(int* __restrict__ bsum) {
    __shared__ int tmp[256];
    int v = (threadIdx.x < SCAN_NB) ? bsum[threadIdx.x] : 0;
    tmp[threadIdx.x] = v;
    __syncthreads();
    for (int off = 1; off < 256; off <<= 1) {
        int t = (threadIdx.x >= off) ? tmp[threadIdx.x - off] : 0;
        __syncthreads();
        tmp[threadIdx.x] += t;
        __syncthreads();
    }
    if (threadIdx.x < SCAN_NB) bsum[threadIdx.x] = tmp[threadIdx.x] - v;  // exclusive
}

__global__ void scan3_kernel(int* __restrict__ rs, const int* __restrict__ bsum) {
    int i = blockIdx.x * 256 + threadIdx.x;
    if (i < N_NODES) rs[i] += bsum[blockIdx.x];
}

__global__ void fill_kernel(const int* __restrict__ src, const int* __restrict__ dst,
                            const int* __restrict__ rs, int* __restrict__ cursor,
                            int* __restrict__ col) {
    int e = blockIdx.x * 256 + threadIdx.x;
    if (e >= N_EDGES) return;
    int d = dst[e];
    int p = atomicAdd(&cursor[d], 1);
    col[rs[d] + p] = src[e];
}

// ---------------- aggregate + GIN prep via global_load_lds ----------------
// One wave processes one node at a time (deg is wave-uniform -> scalar branches).
// Per edge: ONE global_load_lds copies the whole 256B bf16 row into an LDS ring slot
// (lane i gets bytes [4i,4i+4)). Accumulate: 1 ds_read_b32 + unpack + 2 adds per edge.
__global__ __launch_bounds__(256) void agg_kernel(const short* __restrict__ hb,
                                                  const int* __restrict__ rs,
                                                  const int* __restrict__ deg,
                                                  const int* __restrict__ col,
                                                  const float* __restrict__ epsArr, int layer,
                                                  unsigned* __restrict__ z) {
    __shared__ __align__(16) char ring[4][32][256];   // 32 KB: 32-slot ring per wave
    const int wave = threadIdx.x >> 6, lane = threadIdx.x & 63;
    const char* hbase = (const char*)hb;
    char* myring = &ring[wave][0][0];
    const float s = 1.0f + epsArr[layer];

    for (int i = 0; i < 16; ++i) {
        int node = blockIdx.x * 64 + wave * 16 + i;
        float accx = 0.f, accy = 0.f;
        if (node < N_NODES) {
            int start = rs[node], d = deg[node];
            const int* cp = col + start;
            for (int c0 = 0; c0 < d; c0 += 32) {
                int n = d - c0; n = n < 32 ? n : 32;   // wave-uniform
                // WAR guard: prior ds_reads of the ring must complete before refill
                asm volatile("s_waitcnt lgkmcnt(0)" ::: "memory");
                __builtin_amdgcn_sched_barrier(0);
#pragma unroll
                for (int j = 0; j < 32; ++j) {
                    if (j < n) {
                        int idx = cp[c0 + j];
                        gload4(hbase + ((size_t)idx << 8) + (lane << 2), myring + j * 256);
                    }
                }
                asm volatile("s_waitcnt vmcnt(0)" ::: "memory");
                __builtin_amdgcn_sched_barrier(0);
#pragma unroll
                for (int j = 0; j < 32; ++j) {
                    if (j < n) {
                        unsigned u = *(const unsigned*)(myring + j * 256 + (lane << 2));
                        accx += ubits(u << 16);
                        accy += ubits(u & 0xFFFF0000u);
                    }
                }
            }
            unsigned su = *(const unsigned*)(hbase + ((size_t)node << 8) + (lane << 2));
            accx = fmaf(s, ubits(su << 16), accx);
            accy = fmaf(s, ubits(su & 0xFFFF0000u), accy);
        }
        unsigned out = (unsigned)(unsigned short)f2bf(accx)
                     | ((unsigned)(unsigned short)f2bf(accy) << 16);
        z[(size_t)node * 64 + lane] = out;   // bf16 [node][128] row-major
    }
}

// ---------------- fused MLP + LN(+skipLN+ReLU) + residual (R5 kernel) ----------------
// LDS map: [0,32K) W1 then (restaged) W2; [32K,48K) hid; [48K,48K+3K) param vectors.
template <bool LAST>
__global__ __launch_bounds__(256, 2) void mlp_kernel(const short* __restrict__ Z,
                                                     const short* __restrict__ Wt1,
                                                     const float* __restrict__ B1,
                                                     const short* __restrict__ Wt2,
                                                     const float* __restrict__ B2,
                                                     const float* __restrict__ G1,
                                                     const float* __restrict__ Bt1,
                                                     const float* __restrict__ G2,
                                                     const float* __restrict__ Bt2,
                                                     const float* __restrict__ RS,
                                                     float* __restrict__ H,
                                                     short* __restrict__ HB) {
    __shared__ __align__(16) char lds[49152 + 3072];
    const int t = threadIdx.x;
    const int wave = t >> 6, lane = t & 63;
    const int r = lane & 15, kq = lane >> 4;
    const int lrow = wave * 16 + r;
    const int row = blockIdx.x * 64 + lrow;
    const int swzr = (r & 7) << 4;
    const int swzl = (lrow & 7) << 4;
    const int fcol = kq * 16;

    // ---- prefetch Z fragments (needed first) ----
    const short* Zr = Z + (size_t)row * D + kq * 8;
    bf16x8 zb0 = *(const bf16x8*)(Zr);
    bf16x8 zb1 = *(const bf16x8*)(Zr + 32);
    bf16x8 zb2 = *(const bf16x8*)(Zr + 64);
    bf16x8 zb3 = *(const bf16x8*)(Zr + 96);
    __builtin_amdgcn_sched_barrier(0);

    // ---- stage W1 (32KB) + param vectors; issue W2 loads (held in regs) ----
    bf16x8 g2[8];
    {
        bf16x8 g1[8];
#pragma unroll
        for (int i = 0; i < 8; ++i) g1[i] = *(const bf16x8*)(Wt1 + i * 2048 + t * 8);
#pragma unroll
        for (int i = 0; i < 8; ++i) g2[i] = *(const bf16x8*)(Wt2 + i * 2048 + t * 8);
        if (t < (LAST ? 128 : 192)) {
            int which = t >> 5, chunk = t & 31;
            const float* vp = (which == 0) ? B1 : (which == 1) ? B2 : (which == 2) ? G1
                            : (which == 3) ? Bt1 : (which == 4) ? G2 : Bt2;
            *(f32x4*)(lds + 49152 + which * 512 + chunk * 16) = *(const f32x4*)(vp + chunk * 4);
        }
#pragma unroll
        for (int i = 0; i < 8; ++i) {
            int b = i * 4096 + t * 16;
            *(bf16x8*)(lds + (b ^ (((b >> 8) & 7) << 4))) = g1[i];
        }
    }
    __syncthreads();

    // ---- GEMM1 (W1 from LDS) + bias + ReLU -> p[] in regs ----
    bf16x4 p[8];
#pragma unroll
    for (int ct = 0; ct < 8; ++ct) {
        int wb = (ct * 16 + r) * 256 + kq * 16;
        f32x4 acc = {0.f, 0.f, 0.f, 0.f};
        acc = __builtin_amdgcn_mfma_f32_16x16x32_bf16(*(const bf16x8*)(lds + ((wb      ) ^ swzr)), zb0, acc, 0, 0, 0);
        acc = __builtin_amdgcn_mfma_f32_16x16x32_bf16(*(const bf16x8*)(lds + ((wb +  64) ^ swzr)), zb1, acc, 0, 0, 0);
        acc = __builtin_amdgcn_mfma_f32_16x16x32_bf16(*(const bf16x8*)(lds + ((wb + 128) ^ swzr)), zb2, acc, 0, 0, 0);
        acc = __builtin_amdgcn_mfma_f32_16x16x32_bf16(*(const bf16x8*)(lds + ((wb + 192) ^ swzr)), zb3, acc, 0, 0, 0);
        f32x4 bias = *(const f32x4*)(lds + 49152 + 0 + ct * 64 + fcol);
        p[ct][0] = f2bf(fmaxf(acc[0] + bias.x, 0.0f));
        p[ct][1] = f2bf(fmaxf(acc[1] + bias.y, 0.0f));
        p[ct][2] = f2bf(fmaxf(acc[2] + bias.z, 0.0f));
        p[ct][3] = f2bf(fmaxf(acc[3] + bias.w, 0.0f));
    }
    __syncthreads();   // all W1 LDS reads complete

    // ---- issue residual loads (latency hides under GEMM2) ----
    f32x4 rsv[8] = {};
    if (row < N_NODES) {
#pragma unroll
        for (int ct = 0; ct < 8; ++ct)
            rsv[ct] = *(const f32x4*)(RS + (size_t)row * D + ct * 16 + kq * 4);
    }
    __builtin_amdgcn_sched_barrier(0);

    // ---- restage W2 into [0,32K) (regs -> LDS), write hid into [32K,48K) ----
#pragma unroll
    for (int i = 0; i < 8; ++i) {
        int b = i * 4096 + t * 16;
        *(bf16x8*)(lds + (b ^ (((b >> 8) & 7) << 4))) = g2[i];
    }
#pragma unroll
    for (int ct = 0; ct < 8; ++ct)
        *(bf16x4*)(lds + 32768 + ((lrow * 256 + ct * 32 + kq * 8) ^ swzl)) = p[ct];
    __syncthreads();

    // ---- hid B-fragments from LDS ----
    bf16x8 hb0 = *(const bf16x8*)(lds + 32768 + ((lrow * 256 +   0 + kq * 16) ^ swzl));
    bf16x8 hb1 = *(const bf16x8*)(lds + 32768 + ((lrow * 256 +  64 + kq * 16) ^ swzl));
    bf16x8 hb2 = *(const bf16x8*)(lds + 32768 + ((lrow * 256 + 128 + kq * 16) ^ swzl));
    bf16x8 hb3 = *(const bf16x8*)(lds + 32768 + ((lrow * 256 + 192 + kq * 16) ^ swzl));

    // ---- GEMM2 (W2 from LDS) + bias ----
    f32x4 o[8];
#pragma unroll
    for (int ct = 0; ct < 8; ++ct) {
        int wb = (ct * 16 + r) * 256 + kq * 16;
        f32x4 acc = {0.f, 0.f, 0.f, 0.f};
        acc = __builtin_amdgcn_mfma_f32_16x16x32_bf16(*(const bf16x8*)(lds + ((wb      ) ^ swzr)), hb0, acc, 0, 0, 0);
        acc = __builtin_amdgcn_mfma_f32_16x16x32_bf16(*(const bf16x8*)(lds + ((wb +  64) ^ swzr)), hb1, acc, 0, 0, 0);
        acc = __builtin_amdgcn_mfma_f32_16x16x32_bf16(*(const bf16x8*)(lds + ((wb + 128) ^ swzr)), hb2, acc, 0, 0, 0);
        acc = __builtin_amdgcn_mfma_f32_16x16x32_bf16(*(const bf16x8*)(lds + ((wb + 192) ^ swzr)), hb3, acc, 0, 0, 0);
        f32x4 bias = *(const f32x4*)(lds + 49152 + 512 + ct * 64 + fcol);
        o[ct] = acc + bias;
    }

    // ---- LayerNorm over the row ----
    float s = 0.f, q = 0.f;
#pragma unroll
    for (int ct = 0; ct < 8; ++ct) {
        s += o[ct].x + o[ct].y + o[ct].z + o[ct].w;
        q += o[ct].x * o[ct].x + o[ct].y * o[ct].y + o[ct].z * o[ct].z + o[ct].w * o[ct].w;
    }
    s += __shfl_xor(s, 16, 64); q += __shfl_xor(q, 16, 64);
    s += __shfl_xor(s, 32, 64); q += __shfl_xor(q, 32, 64);
    float mu = s * (1.0f / D);
    float rstd = rsqrtf(q * (1.0f / D) - mu * mu + 1e-5f);
#pragma unroll
    for (int ct = 0; ct < 8; ++ct) {
        f32x4 g = *(const f32x4*)(lds + 49152 + 1024 + ct * 64 + fcol);
        f32x4 b = *(const f32x4*)(lds + 49152 + 1536 + ct * 64 + fcol);
        o[ct] = (o[ct] - mu) * rstd * g + b;
    }

    if (!LAST) {
        float s2 = 0.f, q2 = 0.f;
#pragma unroll
        for (int ct = 0; ct < 8; ++ct) {
            s2 += o[ct].x + o[ct].y + o[ct].z + o[ct].w;
            q2 += o[ct].x * o[ct].x + o[ct].y * o[ct].y + o[ct].z * o[ct].z + o[ct].w * o[ct].w;
        }
        s2 += __shfl_xor(s2, 16, 64); q2 += __shfl_xor(q2, 16, 64);
        s2 += __shfl_xor(s2, 32, 64); q2 += __shfl_xor(q2, 32, 64);
        float mu2 = s2 * (1.0f / D);
        float rstd2 = rsqrtf(q2 * (1.0f / D) - mu2 * mu2 + 1e-5f);
#pragma unroll
        for (int ct = 0; ct < 8; ++ct) {
            f32x4 g = *(const f32x4*)(lds + 49152 + 2048 + ct * 64 + fcol);
            f32x4 b = *(const f32x4*)(lds + 49152 + 2560 + ct * 64 + fcol);
            f32x4 y = (o[ct] - mu2) * rstd2 * g + b;
            y.x = fmaxf(y.x, 0.f); y.y = fmaxf(y.y, 0.f);
            y.z = fmaxf(y.z, 0.f); y.w = fmaxf(y.w, 0.f);
            o[ct] = y;
        }
    }

    // ---- residual + store ----
    if (row < N_NODES) {
#pragma unroll
        for (int ct = 0; ct < 8; ++ct) {
            size_t off = (size_t)row * D + ct * 16 + kq * 4;
            f32x4 hv = rsv[ct] + o[ct];
            *(f32x4*)(H + off) = hv;
            if (!LAST) {
                bf16x4 pb;
                pb[0] = f2bf(hv.x); pb[1] = f2bf(hv.y); pb[2] = f2bf(hv.z); pb[3] = f2bf(hv.w);
                *(bf16x4*)(HB + off) = pb;
            }
        }
    }
}

extern "C" void kernel_launch(void* const* d_in, const int* in_sizes, int n_in,
                              void* d_out, int out_size, void* d_ws, size_t ws_size,
                              hipStream_t stream) {
    const float* x   = (const float*)d_in[0];
    const int*   ei  = (const int*)d_in[1];
    const float* eps = (const float*)d_in[2];
    const float* W1  = (const float*)d_in[3];
    const float* b1  = (const float*)d_in[4];
    const float* W2  = (const float*)d_in[5];
    const float* b2  = (const float*)d_in[6];
    const float* lng = (const float*)d_in[7];
    const float* lnb = (const float*)d_in[8];
    const float* skg = (const float*)d_in[9];
    const float* skb = (const float*)d_in[10];
    float* h = (float*)d_out;

    char* ws = (char*)d_ws;
    short* zbuf = (short*)ws;                         // 12,812,288 B
    short* hbb  = (short*)(ws + 12812288);            // 12,812,288 B
    short* wt   = (short*)(ws + 25624576);            //    196,608 B
    int*   rs   = (int*)  (ws + 25821184);            //    200,192 B
    int*   deg  = (int*)  (ws + 26021376);            //    200,192 B
    int*   cur  = (int*)  (ws + 26221568);            //    200,192 B
    int*   col  = (int*)  (ws + 26421760);            //  2,560,000 B
    int*   bsum = (int*)  (ws + 28981760);            //      1,024 B

    const int* srcIdx = ei;
    const int* dstIdx = ei + N_EDGES;

    init_kernel<<<(N_NODES * 32) / 256, 256, 0, stream>>>((const f32x4*)x, (bf16x4*)hbb);
    prepw_kernel<<<(6 * 16384) / 256, 256, 0, stream>>>(W1, W2, wt);

    hipMemsetAsync(deg, 0, 2 * 200192, stream);  // deg + cur contiguous
    hist_kernel<<<(N_EDGES + 255) / 256, 256, 0, stream>>>(dstIdx, deg);
    scan1_kernel<<<SCAN_NB, 256, 0, stream>>>(deg, rs, bsum);
    scan2_kernel<<<1, 256, 0, stream>>>(bsum);
    scan3_kernel<<<SCAN_NB, 256, 0, stream>>>(rs, bsum);
    fill_kernel<<<(N_EDGES + 255) / 256, 256, 0, stream>>>(srcIdx, dstIdx, rs, cur, col);

    for (int l = 0; l < LAYERS; ++l) {
        agg_kernel<<<NPAD / 64, 256, 0, stream>>>(
            hbb, rs, deg, col, eps, l, (unsigned*)zbuf);
        const float* rsrc = (l == 0) ? x : h;
        if (l < LAYERS - 1) {
            mlp_kernel<false><<<NPAD / 64, 256, 0, stream>>>(
                zbuf, wt + l * 16384, b1 + l * D, wt + (3 + l) * 16384, b2 + l * D,
                lng + l * D, lnb + l * D, skg + l * D, skb + l * D, rsrc, h, hbb);
        } else {
            mlp_kernel<true><<<NPAD / 64, 256, 0, stream>>>(
                zbuf, wt + l * 16384, b1 + l * D, wt + (3 + l) * 16384, b2 + l * D,
                lng + l * D, lnb + l * D, nullptr, nullptr, rsrc, h, nullptr);
        }
    }
}

// Round 13
// 224.976 us; speedup vs baseline: 2.0466x; 2.0466x over previous
//
#include <hip/hip_runtime.h>
#include <hip/hip_bf16.h>

#define N_NODES 50000
#define N_EDGES 640000
#define D 128
#define NPAD 50048   // 782 * 64
#define LAYERS 3
#define SCAN_NB 196  // ceil(50000/256)

typedef __attribute__((ext_vector_type(4))) float f32x4;
typedef __attribute__((ext_vector_type(8))) short bf16x8;
typedef __attribute__((ext_vector_type(4))) short bf16x4;

static __device__ __forceinline__ short f2bf(float f) {
    union { float f; unsigned u; } x; x.f = f;
    unsigned r = x.u + 0x7fffu + ((x.u >> 16) & 1u);  // RNE
    return (short)(r >> 16);
}
static __device__ __forceinline__ float bf2f(short s) {
    union { unsigned u; float f; } x; x.u = ((unsigned)(unsigned short)s) << 16;
    return x.f;
}

// ---------------- hb = bf16(x), row-major [node][128] ----------------
__global__ void init_kernel(const f32x4* __restrict__ in, bf16x4* __restrict__ hb) {
    int t = blockIdx.x * 256 + threadIdx.x;
    f32x4 v = in[t];
    bf16x4 p; p[0] = f2bf(v.x); p[1] = f2bf(v.y); p[2] = f2bf(v.z); p[3] = f2bf(v.w);
    hb[t] = p;
}

// ---------------- weights: wt[m][c][k] = bf16(W[m][k][c]) ----------------
__global__ void prepw_kernel(const float* __restrict__ W1, const float* __restrict__ W2,
                             short* __restrict__ wt) {
    int t = blockIdx.x * 256 + threadIdx.x;
    if (t >= 6 * 16384) return;
    int m = t >> 14, rem = t & 16383;
    int c = rem >> 7, k = rem & 127;
    const float* src = (m < 3) ? (W1 + m * 16384) : (W2 + (m - 3) * 16384);
    wt[m * 16384 + c * 128 + k] = f2bf(src[k * 128 + c]);
}

// ---------------- CSR build ----------------
__global__ void hist_kernel(const int* __restrict__ dst, int* __restrict__ deg) {
    int e = blockIdx.x * 256 + threadIdx.x;
    if (e < N_EDGES) atomicAdd(&deg[dst[e]], 1);
}

__global__ void scan1_kernel(const int* __restrict__ deg, int* __restrict__ rs,
                             int* __restrict__ bsum) {
    __shared__ int tmp[256];
    int i = blockIdx.x * 256 + threadIdx.x;
    int v = (i < N_NODES) ? deg[i] : 0;
    tmp[threadIdx.x] = v;
    __syncthreads();
    for (int off = 1; off < 256; off <<= 1) {
        int t = (threadIdx.x >= off) ? tmp[threadIdx.x - off] : 0;
        __syncthreads();
        tmp[threadIdx.x] += t;
        __syncthreads();
    }
    if (i < N_NODES) rs[i] = tmp[threadIdx.x] - v;  // exclusive
    if (threadIdx.x == 255) bsum[blockIdx.x] = tmp[255];
}

__global__ void scan2_kernel(int* __restrict__ bsum) {
    __shared__ int tmp[256];
    int v = (threadIdx.x < SCAN_NB) ? bsum[threadIdx.x] : 0;
    tmp[threadIdx.x] = v;
    __syncthreads();
    for (int off = 1; off < 256; off <<= 1) {
        int t = (threadIdx.x >= off) ? tmp[threadIdx.x - off] : 0;
        __syncthreads();
        tmp[threadIdx.x] += t;
        __syncthreads();
    }
    if (threadIdx.x < SCAN_NB) bsum[threadIdx.x] = tmp[threadIdx.x] - v;  // exclusive
}

__global__ void scan3_kernel(int* __restrict__ rs, const int* __restrict__ bsum) {
    int i = blockIdx.x * 256 + threadIdx.x;
    if (i < N_NODES) rs[i] += bsum[blockIdx.x];
}

__global__ void fill_kernel(const int* __restrict__ src, const int* __restrict__ dst,
                            const int* __restrict__ rs, int* __restrict__ cursor,
                            int* __restrict__ col) {
    int e = blockIdx.x * 256 + threadIdx.x;
    if (e >= N_EDGES) return;
    int d = dst[e];
    int p = atomicAdd(&cursor[d], 1);
    col[rs[d] + p] = src[e];
}

// ---------------- fused aggregate + GIN prep: z = bf16((1+eps)*hb + sum hb[src]) --------
// 16 lanes/node, bf16x8 (16B) per lane. Scalar col loads broadcast across the 16-lane
// group; 4 independent row-gathers in flight. Empirically at the chip's scattered
// line-request rate wall (~2.56M lines/layer @ ~57G lines/s) — see R2..R12 ablations.
__global__ __launch_bounds__(256) void agg_kernel(const bf16x8* __restrict__ hb,
                                                  const int* __restrict__ rs,
                                                  const int* __restrict__ deg,
                                                  const int* __restrict__ col,
                                                  const float* __restrict__ epsArr, int layer,
                                                  bf16x8* __restrict__ z) {
    int t = blockIdx.x * 256 + threadIdx.x;
    int node = t >> 4, lane = t & 15;
    if (node >= NPAD) return;
    bf16x8 o;
    if (node < N_NODES) {
        float acc[8] = {0.f, 0.f, 0.f, 0.f, 0.f, 0.f, 0.f, 0.f};
        int start = rs[node], dg = deg[node];
        const int* cp = col + start;
        int base = 0;
        for (; base + 4 <= dg; base += 4) {
            int c0 = cp[base], c1 = cp[base + 1], c2 = cp[base + 2], c3 = cp[base + 3];
            bf16x8 v0 = hb[(size_t)c0 * 16 + lane];
            bf16x8 v1 = hb[(size_t)c1 * 16 + lane];
            bf16x8 v2 = hb[(size_t)c2 * 16 + lane];
            bf16x8 v3 = hb[(size_t)c3 * 16 + lane];
#pragma unroll
            for (int e = 0; e < 8; ++e)
                acc[e] += (bf2f(v0[e]) + bf2f(v1[e])) + (bf2f(v2[e]) + bf2f(v3[e]));
        }
        for (; base < dg; ++base) {
            bf16x8 v = hb[(size_t)cp[base] * 16 + lane];
#pragma unroll
            for (int e = 0; e < 8; ++e) acc[e] += bf2f(v[e]);
        }
        float s = 1.0f + epsArr[layer];
        bf16x8 hv = hb[(size_t)node * 16 + lane];
#pragma unroll
        for (int e = 0; e < 8; ++e) o[e] = f2bf(fmaf(s, bf2f(hv[e]), acc[e]));
    } else {
        o = (bf16x8)(short)0;
    }
    z[(size_t)node * 16 + lane] = o;
}

// ---------------- fused MLP + LN(+skipLN+ReLU) + residual ----------------
// LDS map: [0,32K) W1 then (restaged) W2; [32K,48K) hid; [48K,48K+3K) param vectors.
// All W/param reads from LDS (R5: removed the per-thread W L2-request storm).
template <bool LAST>
__global__ __launch_bounds__(256, 2) void mlp_kernel(const short* __restrict__ Z,
                                                     const short* __restrict__ Wt1,
                                                     const float* __restrict__ B1,
                                                     const short* __restrict__ Wt2,
                                                     const float* __restrict__ B2,
                                                     const float* __restrict__ G1,
                                                     const float* __restrict__ Bt1,
                                                     const float* __restrict__ G2,
                                                     const float* __restrict__ Bt2,
                                                     const float* __restrict__ RS,
                                                     float* __restrict__ H,
                                                     short* __restrict__ HB) {
    __shared__ __align__(16) char lds[49152 + 3072];
    const int t = threadIdx.x;
    const int wave = t >> 6, lane = t & 63;
    const int r = lane & 15, kq = lane >> 4;
    const int lrow = wave * 16 + r;
    const int row = blockIdx.x * 64 + lrow;
    const int swzr = (r & 7) << 4;
    const int swzl = (lrow & 7) << 4;
    const int fcol = kq * 16;

    // ---- prefetch Z fragments (needed first) ----
    const short* Zr = Z + (size_t)row * D + kq * 8;
    bf16x8 zb0 = *(const bf16x8*)(Zr);
    bf16x8 zb1 = *(const bf16x8*)(Zr + 32);
    bf16x8 zb2 = *(const bf16x8*)(Zr + 64);
    bf16x8 zb3 = *(const bf16x8*)(Zr + 96);
    __builtin_amdgcn_sched_barrier(0);

    // ---- stage W1 (32KB) + param vectors; issue W2 loads (held in regs) ----
    bf16x8 g2[8];
    {
        bf16x8 g1[8];
#pragma unroll
        for (int i = 0; i < 8; ++i) g1[i] = *(const bf16x8*)(Wt1 + i * 2048 + t * 8);
#pragma unroll
        for (int i = 0; i < 8; ++i) g2[i] = *(const bf16x8*)(Wt2 + i * 2048 + t * 8);
        if (t < (LAST ? 128 : 192)) {
            int which = t >> 5, chunk = t & 31;
            const float* vp = (which == 0) ? B1 : (which == 1) ? B2 : (which == 2) ? G1
                            : (which == 3) ? Bt1 : (which == 4) ? G2 : Bt2;
            *(f32x4*)(lds + 49152 + which * 512 + chunk * 16) = *(const f32x4*)(vp + chunk * 4);
        }
#pragma unroll
        for (int i = 0; i < 8; ++i) {
            int b = i * 4096 + t * 16;
            *(bf16x8*)(lds + (b ^ (((b >> 8) & 7) << 4))) = g1[i];
        }
    }
    __syncthreads();

    // ---- GEMM1 (W1 from LDS) + bias + ReLU -> p[] in regs ----
    bf16x4 p[8];
#pragma unroll
    for (int ct = 0; ct < 8; ++ct) {
        int wb = (ct * 16 + r) * 256 + kq * 16;
        f32x4 acc = {0.f, 0.f, 0.f, 0.f};
        acc = __builtin_amdgcn_mfma_f32_16x16x32_bf16(*(const bf16x8*)(lds + ((wb      ) ^ swzr)), zb0, acc, 0, 0, 0);
        acc = __builtin_amdgcn_mfma_f32_16x16x32_bf16(*(const bf16x8*)(lds + ((wb +  64) ^ swzr)), zb1, acc, 0, 0, 0);
        acc = __builtin_amdgcn_mfma_f32_16x16x32_bf16(*(const bf16x8*)(lds + ((wb + 128) ^ swzr)), zb2, acc, 0, 0, 0);
        acc = __builtin_amdgcn_mfma_f32_16x16x32_bf16(*(const bf16x8*)(lds + ((wb + 192) ^ swzr)), zb3, acc, 0, 0, 0);
        f32x4 bias = *(const f32x4*)(lds + 49152 + 0 + ct * 64 + fcol);
        p[ct][0] = f2bf(fmaxf(acc[0] + bias.x, 0.0f));
        p[ct][1] = f2bf(fmaxf(acc[1] + bias.y, 0.0f));
        p[ct][2] = f2bf(fmaxf(acc[2] + bias.z, 0.0f));
        p[ct][3] = f2bf(fmaxf(acc[3] + bias.w, 0.0f));
    }
    __syncthreads();   // all W1 LDS reads complete

    // ---- issue residual loads (latency hides under GEMM2) ----
    f32x4 rsv[8] = {};
    if (row < N_NODES) {
#pragma unroll
        for (int ct = 0; ct < 8; ++ct)
            rsv[ct] = *(const f32x4*)(RS + (size_t)row * D + ct * 16 + kq * 4);
    }
    __builtin_amdgcn_sched_barrier(0);

    // ---- restage W2 into [0,32K) (regs -> LDS), write hid into [32K,48K) ----
#pragma unroll
    for (int i = 0; i < 8; ++i) {
        int b = i * 4096 + t * 16;
        *(bf16x8*)(lds + (b ^ (((b >> 8) & 7) << 4))) = g2[i];
    }
#pragma unroll
    for (int ct = 0; ct < 8; ++ct)
        *(bf16x4*)(lds + 32768 + ((lrow * 256 + ct * 32 + kq * 8) ^ swzl)) = p[ct];
    __syncthreads();

    // ---- hid B-fragments from LDS ----
    bf16x8 hb0 = *(const bf16x8*)(lds + 32768 + ((lrow * 256 +   0 + kq * 16) ^ swzl));
    bf16x8 hb1 = *(const bf16x8*)(lds + 32768 + ((lrow * 256 +  64 + kq * 16) ^ swzl));
    bf16x8 hb2 = *(const bf16x8*)(lds + 32768 + ((lrow * 256 + 128 + kq * 16) ^ swzl));
    bf16x8 hb3 = *(const bf16x8*)(lds + 32768 + ((lrow * 256 + 192 + kq * 16) ^ swzl));

    // ---- GEMM2 (W2 from LDS) + bias ----
    f32x4 o[8];
#pragma unroll
    for (int ct = 0; ct < 8; ++ct) {
        int wb = (ct * 16 + r) * 256 + kq * 16;
        f32x4 acc = {0.f, 0.f, 0.f, 0.f};
        acc = __builtin_amdgcn_mfma_f32_16x16x32_bf16(*(const bf16x8*)(lds + ((wb      ) ^ swzr)), hb0, acc, 0, 0, 0);
        acc = __builtin_amdgcn_mfma_f32_16x16x32_bf16(*(const bf16x8*)(lds + ((wb +  64) ^ swzr)), hb1, acc, 0, 0, 0);
        acc = __builtin_amdgcn_mfma_f32_16x16x32_bf16(*(const bf16x8*)(lds + ((wb + 128) ^ swzr)), hb2, acc, 0, 0, 0);
        acc = __builtin_amdgcn_mfma_f32_16x16x32_bf16(*(const bf16x8*)(lds + ((wb + 192) ^ swzr)), hb3, acc, 0, 0, 0);
        f32x4 bias = *(const f32x4*)(lds + 49152 + 512 + ct * 64 + fcol);
        o[ct] = acc + bias;
    }

    // ---- LayerNorm over the row ----
    float s = 0.f, q = 0.f;
#pragma unroll
    for (int ct = 0; ct < 8; ++ct) {
        s += o[ct].x + o[ct].y + o[ct].z + o[ct].w;
        q += o[ct].x * o[ct].x + o[ct].y * o[ct].y + o[ct].z * o[ct].z + o[ct].w * o[ct].w;
    }
    s += __shfl_xor(s, 16, 64); q += __shfl_xor(q, 16, 64);
    s += __shfl_xor(s, 32, 64); q += __shfl_xor(q, 32, 64);
    float mu = s * (1.0f / D);
    float rstd = rsqrtf(q * (1.0f / D) - mu * mu + 1e-5f);
#pragma unroll
    for (int ct = 0; ct < 8; ++ct) {
        f32x4 g = *(const f32x4*)(lds + 49152 + 1024 + ct * 64 + fcol);
        f32x4 b = *(const f32x4*)(lds + 49152 + 1536 + ct * 64 + fcol);
        o[ct] = (o[ct] - mu) * rstd * g + b;
    }

    if (!LAST) {
        float s2 = 0.f, q2 = 0.f;
#pragma unroll
        for (int ct = 0; ct < 8; ++ct) {
            s2 += o[ct].x + o[ct].y + o[ct].z + o[ct].w;
            q2 += o[ct].x * o[ct].x + o[ct].y * o[ct].y + o[ct].z * o[ct].z + o[ct].w * o[ct].w;
        }
        s2 += __shfl_xor(s2, 16, 64); q2 += __shfl_xor(q2, 16, 64);
        s2 += __shfl_xor(s2, 32, 64); q2 += __shfl_xor(q2, 32, 64);
        float mu2 = s2 * (1.0f / D);
        float rstd2 = rsqrtf(q2 * (1.0f / D) - mu2 * mu2 + 1e-5f);
#pragma unroll
        for (int ct = 0; ct < 8; ++ct) {
            f32x4 g = *(const f32x4*)(lds + 49152 + 2048 + ct * 64 + fcol);
            f32x4 b = *(const f32x4*)(lds + 49152 + 2560 + ct * 64 + fcol);
            f32x4 y = (o[ct] - mu2) * rstd2 * g + b;
            y.x = fmaxf(y.x, 0.f); y.y = fmaxf(y.y, 0.f);
            y.z = fmaxf(y.z, 0.f); y.w = fmaxf(y.w, 0.f);
            o[ct] = y;
        }
    }

    // ---- residual + store ----
    if (row < N_NODES) {
#pragma unroll
        for (int ct = 0; ct < 8; ++ct) {
            size_t off = (size_t)row * D + ct * 16 + kq * 4;
            f32x4 hv = rsv[ct] + o[ct];
            *(f32x4*)(H + off) = hv;
            if (!LAST) {
                bf16x4 pb;
                pb[0] = f2bf(hv.x); pb[1] = f2bf(hv.y); pb[2] = f2bf(hv.z); pb[3] = f2bf(hv.w);
                *(bf16x4*)(HB + off) = pb;
            }
        }
    }
}

extern "C" void kernel_launch(void* const* d_in, const int* in_sizes, int n_in,
                              void* d_out, int out_size, void* d_ws, size_t ws_size,
                              hipStream_t stream) {
    const float* x   = (const float*)d_in[0];
    const int*   ei  = (const int*)d_in[1];
    const float* eps = (const float*)d_in[2];
    const float* W1  = (const float*)d_in[3];
    const float* b1  = (const float*)d_in[4];
    const float* W2  = (const float*)d_in[5];
    const float* b2  = (const float*)d_in[6];
    const float* lng = (const float*)d_in[7];
    const float* lnb = (const float*)d_in[8];
    const float* skg = (const float*)d_in[9];
    const float* skb = (const float*)d_in[10];
    float* h = (float*)d_out;

    char* ws = (char*)d_ws;
    short* zbuf = (short*)ws;                         // 12,812,288 B
    short* hbb  = (short*)(ws + 12812288);            // 12,812,288 B
    short* wt   = (short*)(ws + 25624576);            //    196,608 B
    int*   rs   = (int*)  (ws + 25821184);            //    200,192 B
    int*   deg  = (int*)  (ws + 26021376);            //    200,192 B
    int*   cur  = (int*)  (ws + 26221568);            //    200,192 B
    int*   col  = (int*)  (ws + 26421760);            //  2,560,000 B
    int*   bsum = (int*)  (ws + 28981760);            //      1,024 B

    const int* srcIdx = ei;
    const int* dstIdx = ei + N_EDGES;

    init_kernel<<<(N_NODES * 32) / 256, 256, 0, stream>>>((const f32x4*)x, (bf16x4*)hbb);
    prepw_kernel<<<(6 * 16384) / 256, 256, 0, stream>>>(W1, W2, wt);

    hipMemsetAsync(deg, 0, 2 * 200192, stream);  // deg + cur contiguous
    hist_kernel<<<(N_EDGES + 255) / 256, 256, 0, stream>>>(dstIdx, deg);
    scan1_kernel<<<SCAN_NB, 256, 0, stream>>>(deg, rs, bsum);
    scan2_kernel<<<1, 256, 0, stream>>>(bsum);
    scan3_kernel<<<SCAN_NB, 256, 0, stream>>>(rs, bsum);
    fill_kernel<<<(N_EDGES + 255) / 256, 256, 0, stream>>>(srcIdx, dstIdx, rs, cur, col);

    for (int l = 0; l < LAYERS; ++l) {
        agg_kernel<<<NPAD / 16, 256, 0, stream>>>(
            (const bf16x8*)hbb, rs, deg, col, eps, l, (bf16x8*)zbuf);
        const float* rsrc = (l == 0) ? x : h;
        if (l < LAYERS - 1) {
            mlp_kernel<false><<<NPAD / 64, 256, 0, stream>>>(
                zbuf, wt + l * 16384, b1 + l * D, wt + (3 + l) * 16384, b2 + l * D,
                lng + l * D, lnb + l * D, skg + l * D, skb + l * D, rsrc, h, hbb);
        } else {
            mlp_kernel<true><<<NPAD / 64, 256, 0, stream>>>(
                zbuf, wt + l * 16384, b1 + l * D, wt + (3 + l) * 16384, b2 + l * D,
                lng + l * D, lnb + l * D, nullptr, nullptr, rsrc, h, nullptr);
        }
    }
}